// Round 1
// baseline (639.643 us; speedup 1.0000x reference)
//
#include <hip/hip_runtime.h>
#include <math.h>

// Problem constants (B, N, IN, OUT, H, F) = (4, 2048, 128, 64, 4, 64)
#define BB   4
#define NN   2048
#define IND  128
#define OUTD 64
#define CDIM 256   // H * OUT

#define TI 32      // query rows per block
#define TJ 32      // keys per inner tile

// ---------------------------------------------------------------------------
// Kernel A: per-row features.
//   proj = h @ R ; phi = [cos(proj), sin(proj)]
//   Q = phi @ a_q ; K = phi @ a_k ; Wh = h @ W   (flattened (B*N, 256))
// 8 rows per block to amortize weight reads (R 32KB, aq/ak 32KB, W 128KB from L2).
// ---------------------------------------------------------------------------
__global__ __launch_bounds__(256) void precompute_kernel(
    const float* __restrict__ hg,   // (B*N, 128)
    const float* __restrict__ W,    // (128, 256)
    const float* __restrict__ R,    // (128, 64)
    const float* __restrict__ aq,   // (128, 64)
    const float* __restrict__ ak,   // (128, 64)
    float* __restrict__ Qw,         // (B*N, 64)
    float* __restrict__ Kw,         // (B*N, 64)
    float* __restrict__ Whw)        // (B*N, 256)
{
    const int tid  = threadIdx.x;
    const int row0 = blockIdx.x * 8;

    __shared__ float hs[8][IND];
    __shared__ float phis[8][IND];

    for (int e = tid; e < 8 * IND; e += 256)
        hs[e >> 7][e & 127] = hg[(size_t)row0 * IND + e];
    __syncthreads();

    // proj + phi: 8 rows x 64 features = 512 tasks
    for (int e = tid; e < 512; e += 256) {
        const int r = e >> 6, f = e & 63;
        float p = 0.f;
        #pragma unroll 16
        for (int d = 0; d < IND; ++d) p += hs[r][d] * R[d * 64 + f];
        phis[r][f]      = cosf(p);
        phis[r][f + 64] = sinf(p);
    }

    // Wh: thread owns column c = tid for all 8 rows (W value reused 8x)
    {
        float acc[8] = {0, 0, 0, 0, 0, 0, 0, 0};
        for (int d = 0; d < IND; ++d) {
            const float w = W[d * CDIM + tid];
            #pragma unroll
            for (int r = 0; r < 8; ++r) acc[r] += hs[r][d] * w;
        }
        #pragma unroll
        for (int r = 0; r < 8; ++r)
            Whw[(size_t)(row0 + r) * CDIM + tid] = acc[r];
    }
    __syncthreads();

    // Q / K: o = tid&63, qk selects matrix, rh selects row half (4 rows each)
    {
        const int o  = tid & 63;
        const int qk = (tid >> 6) & 1;
        const int rh = tid >> 7;
        const float* A   = qk ? ak : aq;
        float*       Dst = qk ? Kw : Qw;
        float acc[4] = {0, 0, 0, 0};
        for (int t = 0; t < IND; ++t) {
            const float a = A[t * 64 + o];
            #pragma unroll
            for (int r = 0; r < 4; ++r) acc[r] += phis[rh * 4 + r][t] * a;
        }
        #pragma unroll
        for (int r = 0; r < 4; ++r)
            Dst[(size_t)(row0 + rh * 4 + r) * 64 + o] = acc[r];
    }
}

// ---------------------------------------------------------------------------
// Kernel B: flash-style attention + output projection + ELU.
// One block = 32 query rows of one batch. 256 threads.
//   scores: 2i x 2j micro-tile per thread (LDS padded, conflict-free)
//   PV:     4i x 8c micro-tile per thread, Wh read as contiguous float4
//   epilogue: O/l staged into LDS (reuse Whs), @ output_proj, ELU
// ---------------------------------------------------------------------------
__global__ __launch_bounds__(256) void attn_kernel(
    const float* __restrict__ Qw, const float* __restrict__ Kw,
    const float* __restrict__ Whw,
    const float* __restrict__ pm,      // (B,N,N)
    const float* __restrict__ sm,      // (B,N,N)
    const int*   __restrict__ qm,      // (B,N,N,2)
    const float* __restrict__ qbias,   // (4,4)
    const float* __restrict__ outproj, // (256,64)
    float* __restrict__ out)           // (B*N, 64)
{
    const int tid = threadIdx.x;
    const int blk = blockIdx.x;
    const int b   = blk >> 6;            // 64 i-tiles per batch
    const int i0  = (blk & 63) * TI;

    __shared__ float Qs[TI][65];         // +1 pad: bank-conflict-free dot reads
    __shared__ float Ks[TJ][65];
    __shared__ float Whs[TJ][CDIM];      // also reused for O in epilogue
    __shared__ float Pst[TJ][TI + 1];    // p transposed [j][i]
    __shared__ float row_alpha[TI];
    __shared__ float row_l[TI];
    __shared__ float qb16[16];

    if (tid < 16) qb16[tid] = qbias[tid];

    // stage Q tile (2048 floats)
    {
        const float* src = Qw + (size_t)(b * NN + i0) * 64;
        for (int e = tid * 4; e < TI * 64; e += 1024) {
            const float4 v = *(const float4*)(src + e);
            const int r = e >> 6, o = e & 63;
            Qs[r][o] = v.x; Qs[r][o + 1] = v.y; Qs[r][o + 2] = v.z; Qs[r][o + 3] = v.w;
        }
    }

    // score-thread mapping: rows 2*si, 2*si+1 ; cols 2*sj, 2*sj+1
    const int si = tid >> 4, sj = tid & 15;
    const int ri0 = 2 * si, rj0 = 2 * sj;
    float m0 = -1e30f, m1 = -1e30f, l0 = 0.f, l1 = 0.f;

    // PV-thread mapping: rows ig*4+r ; cols cg*4+k and 128+cg*4+k
    const int ig = tid >> 5, cg = tid & 31;
    float Olo[4][4] = {};
    float Ohi[4][4] = {};

    const float* pmb = pm + ((size_t)b * NN + i0) * NN;
    const float* smb = sm + ((size_t)b * NN + i0) * NN;
    const int*   qmb = qm + ((size_t)b * NN + i0) * NN * 2;

    for (int j0 = 0; j0 < NN; j0 += TJ) {
        __syncthreads();   // previous tile's PV readers done before restaging

        // stage K tile
        {
            const float* src = Kw + (size_t)(b * NN + j0) * 64;
            for (int e = tid * 4; e < TJ * 64; e += 1024) {
                const float4 v = *(const float4*)(src + e);
                const int r = e >> 6, o = e & 63;
                Ks[r][o] = v.x; Ks[r][o + 1] = v.y; Ks[r][o + 2] = v.z; Ks[r][o + 3] = v.w;
            }
        }
        // stage Wh tile (8192 floats, straight float4 copy)
        {
            const float4* src = (const float4*)(Whw + (size_t)(b * NN + j0) * CDIM);
            float4* dst = (float4*)(&Whs[0][0]);
            #pragma unroll
            for (int e = 0; e < 8; ++e) dst[tid + e * 256] = src[tid + e * 256];
        }
        __syncthreads();

        // ---- scores: 2x2 dot micro-tile ----
        float s00 = 0.f, s01 = 0.f, s10 = 0.f, s11 = 0.f;
        #pragma unroll 8
        for (int o = 0; o < 64; ++o) {
            const float q0 = Qs[ri0][o], q1 = Qs[ri0 + 1][o];
            const float k0 = Ks[rj0][o], k1 = Ks[rj0 + 1][o];
            s00 += q0 * k0; s01 += q0 * k1;
            s10 += q1 * k0; s11 += q1 * k1;
        }
        // additive biases
        {
            const size_t base0 = (size_t)ri0 * NN + j0 + rj0;
            const size_t base1 = base0 + NN;
            const float2 p0v = *(const float2*)(pmb + base0);
            const float2 p1v = *(const float2*)(pmb + base1);
            const float2 s0v = *(const float2*)(smb + base0);
            const float2 s1v = *(const float2*)(smb + base1);
            const int4 q0v = *(const int4*)(qmb + base0 * 2);
            const int4 q1v = *(const int4*)(qmb + base1 * 2);
            s00 += p0v.x + s0v.x + qb16[q0v.x * 4 + q0v.y];
            s01 += p0v.y + s0v.y + qb16[q0v.z * 4 + q0v.w];
            s10 += p1v.x + s1v.x + qb16[q1v.x * 4 + q1v.y];
            s11 += p1v.y + s1v.y + qb16[q1v.z * 4 + q1v.w];
        }
        // ---- online softmax (row state wave-local: 16 lanes per row-pair) ----
        float tm0 = fmaxf(s00, s01), tm1 = fmaxf(s10, s11);
        #pragma unroll
        for (int msk = 1; msk <= 8; msk <<= 1) {
            tm0 = fmaxf(tm0, __shfl_xor(tm0, msk, 64));
            tm1 = fmaxf(tm1, __shfl_xor(tm1, msk, 64));
        }
        const float mn0 = fmaxf(m0, tm0), mn1 = fmaxf(m1, tm1);
        const float p00 = __expf(s00 - mn0), p01 = __expf(s01 - mn0);
        const float p10 = __expf(s10 - mn1), p11 = __expf(s11 - mn1);
        float ts0 = p00 + p01, ts1 = p10 + p11;
        #pragma unroll
        for (int msk = 1; msk <= 8; msk <<= 1) {
            ts0 += __shfl_xor(ts0, msk, 64);
            ts1 += __shfl_xor(ts1, msk, 64);
        }
        const float al0 = __expf(m0 - mn0), al1 = __expf(m1 - mn1);
        l0 = l0 * al0 + ts0;  l1 = l1 * al1 + ts1;
        m0 = mn0;             m1 = mn1;

        Pst[rj0][ri0]         = p00; Pst[rj0 + 1][ri0]     = p01;
        Pst[rj0][ri0 + 1]     = p10; Pst[rj0 + 1][ri0 + 1] = p11;
        if (sj == 0) { row_alpha[ri0] = al0; row_alpha[ri0 + 1] = al1; }
        __syncthreads();

        // ---- PV: O = O*alpha + P @ Wh ----
        {
            float av[4];
            #pragma unroll
            for (int r = 0; r < 4; ++r) av[r] = row_alpha[ig * 4 + r];
            #pragma unroll
            for (int r = 0; r < 4; ++r)
                #pragma unroll
                for (int k = 0; k < 4; ++k) { Olo[r][k] *= av[r]; Ohi[r][k] *= av[r]; }

            #pragma unroll 4
            for (int j = 0; j < TJ; ++j) {
                float pv[4];
                #pragma unroll
                for (int r = 0; r < 4; ++r) pv[r] = Pst[j][ig * 4 + r];
                const float4 wl = *(const float4*)(&Whs[j][cg * 4]);
                const float4 wh = *(const float4*)(&Whs[j][128 + cg * 4]);
                const float wlv[4] = {wl.x, wl.y, wl.z, wl.w};
                const float whv[4] = {wh.x, wh.y, wh.z, wh.w};
                #pragma unroll
                for (int r = 0; r < 4; ++r)
                    #pragma unroll
                    for (int k = 0; k < 4; ++k) {
                        Olo[r][k] += pv[r] * wlv[k];
                        Ohi[r][k] += pv[r] * whv[k];
                    }
            }
        }
    }

    // ---- finalize: publish l, normalize O into LDS (reuse Whs) ----
    if (sj == 0) { row_l[ri0] = l0; row_l[ri0 + 1] = l1; }
    __syncthreads();   // also guarantees all PV reads of Whs are done
    {
        #pragma unroll
        for (int r = 0; r < 4; ++r) {
            const float inv = 1.f / row_l[ig * 4 + r];
            *(float4*)(&Whs[ig * 4 + r][cg * 4]) =
                make_float4(Olo[r][0] * inv, Olo[r][1] * inv, Olo[r][2] * inv, Olo[r][3] * inv);
            *(float4*)(&Whs[ig * 4 + r][128 + cg * 4]) =
                make_float4(Ohi[r][0] * inv, Ohi[r][1] * inv, Ohi[r][2] * inv, Ohi[r][3] * inv);
        }
    }
    __syncthreads();

    // ---- output projection + ELU: rows io*8+m, col o ----
    {
        const int o  = tid & 63;
        const int io = tid >> 6;
        float acc[8] = {};
        for (int c = 0; c < CDIM; ++c) {
            const float w = outproj[c * 64 + o];
            #pragma unroll
            for (int mr = 0; mr < 8; ++mr) acc[mr] += Whs[io * 8 + mr][c] * w;
        }
        float* dst = out + ((size_t)(b * NN) + i0 + io * 8) * 64 + o;
        #pragma unroll
        for (int mr = 0; mr < 8; ++mr) {
            float x = acc[mr];
            x = x > 0.f ? x : (__expf(x) - 1.f);
            dst[mr * 64] = x;
        }
    }
}

// ---------------------------------------------------------------------------
extern "C" void kernel_launch(void* const* d_in, const int* in_sizes, int n_in,
                              void* d_out, int out_size, void* d_ws, size_t ws_size,
                              hipStream_t stream) {
    (void)in_sizes; (void)n_in; (void)out_size; (void)ws_size;
    const float* h  = (const float*)d_in[0];
    const float* pm = (const float*)d_in[1];
    const float* sm = (const float*)d_in[2];
    const float* W  = (const float*)d_in[3];
    const float* R  = (const float*)d_in[4];
    const float* aq = (const float*)d_in[5];
    const float* ak = (const float*)d_in[6];
    const float* qb = (const float*)d_in[7];
    const float* op = (const float*)d_in[8];
    const int*   qm = (const int*)d_in[9];
    float* out = (float*)d_out;

    float* ws  = (float*)d_ws;
    float* Qw  = ws;                               // 4*2048*64  = 0.5M floats
    float* Kw  = ws + (size_t)BB * NN * 64;        // 0.5M floats
    float* Whw = ws + (size_t)BB * NN * 64 * 2;    // 2M floats  (12 MB total)

    precompute_kernel<<<BB * NN / 8, 256, 0, stream>>>(h, W, R, aq, ak, Qw, Kw, Whw);
    attn_kernel<<<BB * (NN / TI), 256, 0, stream>>>(Qw, Kw, Whw, pm, sm, qm, qb, op, out);
}

// Round 2
// 486.925 us; speedup vs baseline: 1.3136x; 1.3136x over previous
//
#include <hip/hip_runtime.h>
#include <math.h>

// Problem constants (B, N, IN, OUT, H, F) = (4, 2048, 128, 64, 4, 64)
#define BB   4
#define NN   2048
#define IND  128
#define CDIM 256        // H * OUT
#define TI   32         // query rows per block
#define TJ   32         // keys per inner tile
#define NG   4          // in-block j-split groups (wave-aligned: 4 waves each)
#define JCHUNK (NN / NG)      // 512
#define NTILES (JCHUNK / TJ)  // 16

// ---- bf16 helpers (OCP bf16 as raw ushort; RNE rounding) -------------------
__device__ __forceinline__ float bfu2f_lo(unsigned u) {       // low 16 bits
    return __uint_as_float(u << 16);
}
__device__ __forceinline__ float bfu2f_hi(unsigned u) {       // high 16 bits
    return __uint_as_float(u & 0xffff0000u);
}
__device__ __forceinline__ unsigned short f2bf(float f) {
    unsigned u = __float_as_uint(f);
    u = (u + 0x7fffu + ((u >> 16) & 1u)) >> 16;
    return (unsigned short)u;
}
__device__ __forceinline__ unsigned pack2bf(float lo, float hi) {
    return (unsigned)f2bf(lo) | ((unsigned)f2bf(hi) << 16);
}

// ---------------------------------------------------------------------------
// Kernel A: per-row features. 16 rows/block, 512 blocks.
//   phi = [cos(hR), sin(hR)]; Q = phi@aq; K = phi@ak; Wh = h@W (stored bf16)
// Register micro-tiles amortize each weight load over 4..16 FMAs.
// ---------------------------------------------------------------------------
__global__ __launch_bounds__(256) void precompute_kernel(
    const float* __restrict__ hg,   // (B*N, 128)
    const float* __restrict__ W,    // (128, 256)
    const float* __restrict__ R,    // (128, 64)
    const float* __restrict__ aq,   // (128, 64)
    const float* __restrict__ ak,   // (128, 64)
    float* __restrict__ Qw,         // (B*N, 64)
    float* __restrict__ Kw,         // (B*N, 64)
    unsigned short* __restrict__ Whw) // (B*N, 256) bf16
{
    const int tid  = threadIdx.x;
    const int row0 = blockIdx.x * 16;

    __shared__ float hs[16][IND];    // 8 KB
    __shared__ float phis[16][IND];  // 8 KB

    {
        const float4* src = (const float4*)(hg + (size_t)row0 * IND);
        float4* dst = (float4*)&hs[0][0];
        dst[tid]       = src[tid];
        dst[tid + 256] = src[tid + 256];
    }
    __syncthreads();

    // phi: thread owns feature f for rows {rr, rr+4, rr+8, rr+12}
    {
        const int f  = tid & 63;
        const int rr = tid >> 6;    // 0..3
        float p0 = 0.f, p1 = 0.f, p2 = 0.f, p3 = 0.f;
        #pragma unroll 8
        for (int d = 0; d < IND; ++d) {
            const float rv = R[d * 64 + f];
            p0 += hs[rr][d] * rv;      p1 += hs[rr + 4][d] * rv;
            p2 += hs[rr + 8][d] * rv;  p3 += hs[rr + 12][d] * rv;
        }
        float s, c;
        __sincosf(p0, &s, &c); phis[rr][f]      = c; phis[rr][f + 64]      = s;
        __sincosf(p1, &s, &c); phis[rr + 4][f]  = c; phis[rr + 4][f + 64]  = s;
        __sincosf(p2, &s, &c); phis[rr + 8][f]  = c; phis[rr + 8][f + 64]  = s;
        __sincosf(p3, &s, &c); phis[rr + 12][f] = c; phis[rr + 12][f + 64] = s;
    }

    // Wh: thread owns column tid for all 16 rows (W value reused 16x)
    {
        float acc[16];
        #pragma unroll
        for (int r = 0; r < 16; ++r) acc[r] = 0.f;
        #pragma unroll 4
        for (int d = 0; d < IND; ++d) {
            const float w = W[d * CDIM + tid];
            #pragma unroll
            for (int r = 0; r < 16; ++r) acc[r] += hs[r][d] * w;
        }
        #pragma unroll
        for (int r = 0; r < 16; ++r)
            Whw[(size_t)(row0 + r) * CDIM + tid] = f2bf(acc[r]);
    }
    __syncthreads();

    // Q/K: o = tid&63, qk selects matrix, rh selects 8-row half
    {
        const int o  = tid & 63;
        const int qk = (tid >> 6) & 1;
        const int rh = tid >> 7;
        const float* A   = qk ? ak : aq;
        float*       Dst = qk ? Kw : Qw;
        float acc[8];
        #pragma unroll
        for (int r = 0; r < 8; ++r) acc[r] = 0.f;
        #pragma unroll 4
        for (int tt = 0; tt < IND; ++tt) {
            const float a = A[tt * 64 + o];
            #pragma unroll
            for (int r = 0; r < 8; ++r) acc[r] += phis[rh * 8 + r][tt] * a;
        }
        #pragma unroll
        for (int r = 0; r < 8; ++r)
            Dst[(size_t)(row0 + rh * 8 + r) * 64 + o] = acc[r];
    }
}

// ---------------------------------------------------------------------------
// Kernel B: flash attention + output projection + ELU.
// 1024 threads = 4 wave-groups; group g owns j in [g*512, (g+1)*512).
// All groups share the same 32-row i-tile; partials (m,l,O) combined in LDS.
// 16 waves/CU (1 block/CU, 143 KB LDS) vs round-1's 4 waves/CU.
// ---------------------------------------------------------------------------
__global__ __launch_bounds__(1024, 4) void attn_kernel(
    const float* __restrict__ Qw, const float* __restrict__ Kw,
    const unsigned short* __restrict__ Whw,   // bf16
    const float* __restrict__ pm,      // (B,N,N)
    const float* __restrict__ sm,      // (B,N,N)
    const int*   __restrict__ qm,      // (B,N,N,2)
    const float* __restrict__ qbias,   // (4,4)
    const float* __restrict__ outproj, // (256,64)
    float* __restrict__ out)           // (B*N, 64)
{
    const int tid = threadIdx.x;
    const int g   = tid >> 8;          // wave-group 0..3
    const int t   = tid & 255;
    const int blk = blockIdx.x;
    // XCD swizzle: batch = (blk%8)/2 so one batch's K+Wh (1.5MB) lives per-XCD L2
    const int b   = (blk & 7) >> 1;
    const int i0  = (((blk >> 3) << 1) | (blk & 1)) * TI;

    __shared__ float Qs[TI][68];                        //  8704 B (68: 16B-aligned rows, conflict-spread)
    __shared__ float Ks[NG][TJ][68];                    // 34816 B
    __shared__ unsigned short Whs[NG][TJ][CDIM];        // 65536 B (bf16)
    __shared__ float Pst[NG][TJ][36];                   // 18432 B (P transposed [j][i], 36: 16B-aligned)
    __shared__ float Alpha[NG][TI];                     //   512 B
    __shared__ float Ml[NG][TI];                        //   512 B
    __shared__ float Ll[NG][TI];                        //   512 B
    __shared__ unsigned short Osum[TI][264];            // 16896 B (bf16 hp accumulator)
    __shared__ float qb16[16];

    if (tid < 16) qb16[tid] = qbias[tid];
    if (tid < 512) {
        const float4 v = ((const float4*)(Qw + (size_t)(b * NN + i0) * 64))[tid];
        const int r = tid >> 4, c4 = tid & 15;
        *(float4*)&Qs[r][c4 * 4] = v;
    }

    // scores layout: rows 2si,2si+1 ; cols 2sj,2sj+1 (within group's j-tile)
    const int si = t >> 4, sj = t & 15;
    const int ri0 = 2 * si, rj0 = 2 * sj;
    float m0 = -1e30f, m1 = -1e30f, l0 = 0.f, l1 = 0.f;

    // PV layout: rows ig*4+r ; cols cg*8..cg*8+7
    const int ig = t >> 5, cg = t & 31;
    float Oa[4][8];
    #pragma unroll
    for (int r = 0; r < 4; ++r)
        #pragma unroll
        for (int k = 0; k < 8; ++k) Oa[r][k] = 0.f;

    const float* pmb = pm + ((size_t)b * NN + i0) * NN;
    const float* smb = sm + ((size_t)b * NN + i0) * NN;
    const int*   qmb = qm + ((size_t)b * NN + i0) * NN * 2;

    for (int tile = 0; tile < NTILES; ++tile) {
        const int j0 = g * JCHUNK + tile * TJ;
        __syncthreads();   // prior PV readers done before restaging

        // stage K tile (fp32, padded rows)
        {
            const float4* src = (const float4*)(Kw + (size_t)(b * NN + j0) * 64);
            #pragma unroll
            for (int kk = 0; kk < 2; ++kk) {
                const int e = t + kk * 256;
                const float4 v = src[e];
                const int r = e >> 4, c4 = e & 15;
                *(float4*)&Ks[g][r][c4 * 4] = v;
            }
        }
        // stage Wh tile (bf16, contiguous copy)
        {
            const uint4* src = (const uint4*)(Whw + (size_t)(b * NN + j0) * CDIM);
            uint4* dst = (uint4*)&Whs[g][0][0];
            #pragma unroll
            for (int kk = 0; kk < 4; ++kk) dst[t + kk * 256] = src[t + kk * 256];
        }
        __syncthreads();

        // ---- scores: 2x2 micro-tile, float4 LDS reads ----
        float s00 = 0.f, s01 = 0.f, s10 = 0.f, s11 = 0.f;
        #pragma unroll 4
        for (int o4 = 0; o4 < 16; ++o4) {
            const float4 q0 = *(const float4*)&Qs[ri0][o4 * 4];
            const float4 q1 = *(const float4*)&Qs[ri0 + 1][o4 * 4];
            const float4 k0 = *(const float4*)&Ks[g][rj0][o4 * 4];
            const float4 k1 = *(const float4*)&Ks[g][rj0 + 1][o4 * 4];
            s00 += q0.x * k0.x + q0.y * k0.y + q0.z * k0.z + q0.w * k0.w;
            s01 += q0.x * k1.x + q0.y * k1.y + q0.z * k1.z + q0.w * k1.w;
            s10 += q1.x * k0.x + q1.y * k0.y + q1.z * k0.z + q1.w * k0.w;
            s11 += q1.x * k1.x + q1.y * k1.y + q1.z * k1.z + q1.w * k1.w;
        }
        // additive biases (streamed once from HBM — the mandatory traffic)
        {
            const size_t base0 = (size_t)ri0 * NN + j0 + rj0;
            const size_t base1 = base0 + NN;
            const float2 p0v = *(const float2*)(pmb + base0);
            const float2 p1v = *(const float2*)(pmb + base1);
            const float2 s0v = *(const float2*)(smb + base0);
            const float2 s1v = *(const float2*)(smb + base1);
            const int4 q0v = *(const int4*)(qmb + base0 * 2);
            const int4 q1v = *(const int4*)(qmb + base1 * 2);
            s00 += p0v.x + s0v.x + qb16[q0v.x * 4 + q0v.y];
            s01 += p0v.y + s0v.y + qb16[q0v.z * 4 + q0v.w];
            s10 += p1v.x + s1v.x + qb16[q1v.x * 4 + q1v.y];
            s11 += p1v.y + s1v.y + qb16[q1v.z * 4 + q1v.w];
        }
        // ---- online softmax (rows live in 16-lane groups of one wave) ----
        float tm0 = fmaxf(s00, s01), tm1 = fmaxf(s10, s11);
        #pragma unroll
        for (int msk = 1; msk <= 8; msk <<= 1) {
            tm0 = fmaxf(tm0, __shfl_xor(tm0, msk, 64));
            tm1 = fmaxf(tm1, __shfl_xor(tm1, msk, 64));
        }
        const float mn0 = fmaxf(m0, tm0), mn1 = fmaxf(m1, tm1);
        const float p00 = __expf(s00 - mn0), p01 = __expf(s01 - mn0);
        const float p10 = __expf(s10 - mn1), p11 = __expf(s11 - mn1);
        float ts0 = p00 + p01, ts1 = p10 + p11;
        #pragma unroll
        for (int msk = 1; msk <= 8; msk <<= 1) {
            ts0 += __shfl_xor(ts0, msk, 64);
            ts1 += __shfl_xor(ts1, msk, 64);
        }
        const float al0 = __expf(m0 - mn0), al1 = __expf(m1 - mn1);
        l0 = l0 * al0 + ts0;  l1 = l1 * al1 + ts1;
        m0 = mn0;             m1 = mn1;

        Pst[g][rj0][ri0]         = p00; Pst[g][rj0 + 1][ri0]     = p01;
        Pst[g][rj0][ri0 + 1]     = p10; Pst[g][rj0 + 1][ri0 + 1] = p11;
        if (sj == 0) { Alpha[g][ri0] = al0; Alpha[g][ri0 + 1] = al1; }
        __syncthreads();

        // ---- PV: O = O*alpha + P @ Wh(bf16) ----
        {
            float av[4];
            #pragma unroll
            for (int r = 0; r < 4; ++r) av[r] = Alpha[g][ig * 4 + r];
            #pragma unroll
            for (int r = 0; r < 4; ++r)
                #pragma unroll
                for (int k = 0; k < 8; ++k) Oa[r][k] *= av[r];

            #pragma unroll 4
            for (int j = 0; j < TJ; ++j) {
                const float4 pvv = *(const float4*)&Pst[g][j][ig * 4];
                const float pv[4] = {pvv.x, pvv.y, pvv.z, pvv.w};
                const uint4 wv = *(const uint4*)&Whs[g][j][cg * 8];
                float w[8];
                w[0] = bfu2f_lo(wv.x); w[1] = bfu2f_hi(wv.x);
                w[2] = bfu2f_lo(wv.y); w[3] = bfu2f_hi(wv.y);
                w[4] = bfu2f_lo(wv.z); w[5] = bfu2f_hi(wv.z);
                w[6] = bfu2f_lo(wv.w); w[7] = bfu2f_hi(wv.w);
                #pragma unroll
                for (int r = 0; r < 4; ++r)
                    #pragma unroll
                    for (int k = 0; k < 8; ++k) Oa[r][k] += pv[r] * w[k];
            }
        }
    }

    // ---- epilogue: combine 4 group-partials, project, ELU ----
    if (sj == 0) {
        Ml[g][ri0] = m0; Ml[g][ri0 + 1] = m1;
        Ll[g][ri0] = l0; Ll[g][ri0 + 1] = l1;
    }
    __syncthreads();   // also fences last PV reads of Whs

    // scaled partial O (bf16) into own group's Whs area
    {
        #pragma unroll
        for (int r = 0; r < 4; ++r) {
            const int row = ig * 4 + r;
            const float M = fmaxf(fmaxf(Ml[0][row], Ml[1][row]),
                                  fmaxf(Ml[2][row], Ml[3][row]));
            const float sc = __expf(Ml[g][row] - M);
            uint4 pk;
            pk.x = pack2bf(Oa[r][0] * sc, Oa[r][1] * sc);
            pk.y = pack2bf(Oa[r][2] * sc, Oa[r][3] * sc);
            pk.z = pack2bf(Oa[r][4] * sc, Oa[r][5] * sc);
            pk.w = pack2bf(Oa[r][6] * sc, Oa[r][7] * sc);
            *(uint4*)&Whs[g][row][cg * 8] = pk;
        }
    }
    __syncthreads();

    // cross-group sum -> Osum (hp, bf16)
    {
        const int row = tid >> 5;
        const int c0  = (tid & 31) * 8;
        float s[8] = {0.f, 0.f, 0.f, 0.f, 0.f, 0.f, 0.f, 0.f};
        #pragma unroll
        for (int gg = 0; gg < NG; ++gg) {
            const uint4 v = *(const uint4*)&Whs[gg][row][c0];
            s[0] += bfu2f_lo(v.x); s[1] += bfu2f_hi(v.x);
            s[2] += bfu2f_lo(v.y); s[3] += bfu2f_hi(v.y);
            s[4] += bfu2f_lo(v.z); s[5] += bfu2f_hi(v.z);
            s[6] += bfu2f_lo(v.w); s[7] += bfu2f_hi(v.w);
        }
        uint4 pk;
        pk.x = pack2bf(s[0], s[1]); pk.y = pack2bf(s[2], s[3]);
        pk.z = pack2bf(s[4], s[5]); pk.w = pack2bf(s[6], s[7]);
        *(uint4*)&Osum[row][c0] = pk;
    }
    __syncthreads();

    // hp @ outproj + ELU: thread -> col o, rows r0 and r0+16
    {
        const int o  = tid & 63;
        const int r0 = tid >> 6;    // 0..15
        float acc0 = 0.f, acc1 = 0.f;
        #pragma unroll 4
        for (int c = 0; c < CDIM; ++c) {
            const float w = outproj[c * 64 + o];
            acc0 += bfu2f_lo((unsigned)Osum[r0][c])      * w;
            acc1 += bfu2f_lo((unsigned)Osum[r0 + 16][c]) * w;
        }
        float M0 = fmaxf(fmaxf(Ml[0][r0], Ml[1][r0]), fmaxf(Ml[2][r0], Ml[3][r0]));
        float lt0 = Ll[0][r0] * __expf(Ml[0][r0] - M0) + Ll[1][r0] * __expf(Ml[1][r0] - M0)
                  + Ll[2][r0] * __expf(Ml[2][r0] - M0) + Ll[3][r0] * __expf(Ml[3][r0] - M0);
        const int r1 = r0 + 16;
        float M1 = fmaxf(fmaxf(Ml[0][r1], Ml[1][r1]), fmaxf(Ml[2][r1], Ml[3][r1]));
        float lt1 = Ll[0][r1] * __expf(Ml[0][r1] - M1) + Ll[1][r1] * __expf(Ml[1][r1] - M1)
                  + Ll[2][r1] * __expf(Ml[2][r1] - M1) + Ll[3][r1] * __expf(Ml[3][r1] - M1);
        float x0 = acc0 / lt0;
        float x1 = acc1 / lt1;
        x0 = x0 > 0.f ? x0 : (__expf(x0) - 1.f);
        x1 = x1 > 0.f ? x1 : (__expf(x1) - 1.f);
        out[((size_t)(b * NN) + i0 + r0) * 64 + o] = x0;
        out[((size_t)(b * NN) + i0 + r1) * 64 + o] = x1;
    }
}

// ---------------------------------------------------------------------------
extern "C" void kernel_launch(void* const* d_in, const int* in_sizes, int n_in,
                              void* d_out, int out_size, void* d_ws, size_t ws_size,
                              hipStream_t stream) {
    (void)in_sizes; (void)n_in; (void)out_size; (void)ws_size;
    const float* h  = (const float*)d_in[0];
    const float* pm = (const float*)d_in[1];
    const float* sm = (const float*)d_in[2];
    const float* W  = (const float*)d_in[3];
    const float* R  = (const float*)d_in[4];
    const float* aq = (const float*)d_in[5];
    const float* ak = (const float*)d_in[6];
    const float* qb = (const float*)d_in[7];
    const float* op = (const float*)d_in[8];
    const int*   qm = (const int*)d_in[9];
    float* out = (float*)d_out;

    float* ws = (float*)d_ws;
    float* Qw = ws;                                   // 0.5M floats (2 MB)
    float* Kw = ws + (size_t)BB * NN * 64;            // 0.5M floats (2 MB)
    unsigned short* Whw = (unsigned short*)(ws + (size_t)BB * NN * 64 * 2); // 2M bf16 (4 MB)

    precompute_kernel<<<BB * NN / 16, 256, 0, stream>>>(h, W, R, aq, ak, Qw, Kw, Whw);
    attn_kernel<<<BB * (NN / TI), 1024, 0, stream>>>(Qw, Kw, Whw, pm, sm, qm, qb, op, out);
}

// Round 3
// 397.231 us; speedup vs baseline: 1.6103x; 1.2258x over previous
//
#include <hip/hip_runtime.h>
#include <math.h>

// (B, N, IN, OUT, H, F) = (4, 2048, 128, 64, 4, 64)
#define BB   4
#define NN   2048
#define IND  128
#define CDIM 256          // H*OUT
#define TIW  32           // i-tile rows per block
#define TJW  64           // j-tile per iteration
#define NIT  (NN / TJW)   // 32 iterations

typedef _Float16 half_t;
typedef _Float16 half4_t __attribute__((ext_vector_type(4)));
typedef _Float16 half8_t __attribute__((ext_vector_type(8)));
typedef float    f32x4   __attribute__((ext_vector_type(4)));

// ---------------------------------------------------------------------------
// Kernel A: per-row features -> f16 Q, K (row-major) and Wh^T (B,256,N) f16.
// ---------------------------------------------------------------------------
__global__ __launch_bounds__(256) void precompute_kernel(
    const float* __restrict__ hg,   // (B*N, 128)
    const float* __restrict__ W,    // (128, 256)
    const float* __restrict__ R,    // (128, 64)
    const float* __restrict__ aq,   // (128, 64)
    const float* __restrict__ ak,   // (128, 64)
    half_t* __restrict__ Qw,        // (B*N, 64) f16
    half_t* __restrict__ Kw,        // (B*N, 64) f16
    half_t* __restrict__ WhT)       // (B, 256, N) f16 (transposed!)
{
    const int tid  = threadIdx.x;
    const int row0 = blockIdx.x * 16;

    __shared__ float hs[16][IND];
    __shared__ float phis[16][IND];

    {
        const float4* src = (const float4*)(hg + (size_t)row0 * IND);
        float4* dst = (float4*)&hs[0][0];
        dst[tid]       = src[tid];
        dst[tid + 256] = src[tid + 256];
    }
    __syncthreads();

    // phi: thread -> feature f for rows {rr, rr+4, rr+8, rr+12}
    {
        const int f  = tid & 63;
        const int rr = tid >> 6;
        float p0 = 0.f, p1 = 0.f, p2 = 0.f, p3 = 0.f;
        #pragma unroll 8
        for (int d = 0; d < IND; ++d) {
            const float rv = R[d * 64 + f];
            p0 += hs[rr][d] * rv;      p1 += hs[rr + 4][d] * rv;
            p2 += hs[rr + 8][d] * rv;  p3 += hs[rr + 12][d] * rv;
        }
        float s, c;
        __sincosf(p0, &s, &c); phis[rr][f]      = c; phis[rr][f + 64]      = s;
        __sincosf(p1, &s, &c); phis[rr + 4][f]  = c; phis[rr + 4][f + 64]  = s;
        __sincosf(p2, &s, &c); phis[rr + 8][f]  = c; phis[rr + 8][f + 64]  = s;
        __sincosf(p3, &s, &c); phis[rr + 12][f] = c; phis[rr + 12][f + 64] = s;
    }

    // Wh: thread owns column c = tid for all 16 rows; store transposed f16.
    {
        float acc[16];
        #pragma unroll
        for (int r = 0; r < 16; ++r) acc[r] = 0.f;
        #pragma unroll 4
        for (int d = 0; d < IND; ++d) {
            const float w = W[d * CDIM + tid];
            #pragma unroll
            for (int r = 0; r < 16; ++r) acc[r] += hs[r][d] * w;
        }
        const int brow = row0 >> 11;       // batch
        const int n0   = row0 & (NN - 1);  // row within batch (16-aligned)
        half8_t v0, v1;
        #pragma unroll
        for (int r = 0; r < 8; ++r) { v0[r] = (half_t)acc[r]; v1[r] = (half_t)acc[r + 8]; }
        half8_t* dst = (half8_t*)(WhT + ((size_t)brow * CDIM + tid) * NN + n0);
        dst[0] = v0; dst[1] = v1;
    }
    __syncthreads();

    // Q/K: o = tid&63, qk selects matrix, rh selects 8-row half; f16 out.
    {
        const int o  = tid & 63;
        const int qk = (tid >> 6) & 1;
        const int rh = tid >> 7;
        const float* A = qk ? ak : aq;
        half_t*    Dst = qk ? Kw : Qw;
        float acc[8];
        #pragma unroll
        for (int r = 0; r < 8; ++r) acc[r] = 0.f;
        #pragma unroll 4
        for (int tt = 0; tt < IND; ++tt) {
            const float a = A[tt * 64 + o];
            #pragma unroll
            for (int r = 0; r < 8; ++r) acc[r] += phis[rh * 8 + r][tt] * a;
        }
        #pragma unroll
        for (int r = 0; r < 8; ++r)
            Dst[(size_t)(row0 + rh * 8 + r) * 64 + o] = (half_t)acc[r];
    }
}

// ---------------------------------------------------------------------------
// Tiny kernel: transpose output projection to (64, 256) f16 for the epilogue.
// ---------------------------------------------------------------------------
__global__ __launch_bounds__(256) void prep_opT_kernel(
    const float* __restrict__ op, half_t* __restrict__ opT)
{
    const int t = blockIdx.x * 256 + threadIdx.x;   // 16384
    const int c = t >> 6, o = t & 63;
    opT[o * CDIM + c] = (half_t)op[c * 64 + o];
}

// ---------------------------------------------------------------------------
// Kernel B: MFMA flash attention + projection + ELU.
// 1024 thr = 16 waves = (row-half rh:2) x (comb cb:4) x (duty:2).
//  duty0 waves: scores (mfma f16) + bias + wave-private online softmax -> P
//  duty1 waves: double-buffered staging of K / Wh^T tiles
//  all waves:   PV mfma on their 128-col half.  Combs merged once at end.
// ---------------------------------------------------------------------------
__global__ __launch_bounds__(1024, 4) void attn_kernel(
    const half_t* __restrict__ Qw, const half_t* __restrict__ Kw,
    const half_t* __restrict__ WhT,
    const float* __restrict__ pm,      // (B,N,N)
    const float* __restrict__ sm,      // (B,N,N)
    const int*   __restrict__ qm,      // (B,N,N,2)
    const float* __restrict__ qbias,   // (4,4)
    const half_t* __restrict__ opT,    // (64,256) f16
    float* __restrict__ out)           // (B*N, 64)
{
    const int tid  = threadIdx.x;
    const int w    = tid >> 6;
    const int lane = tid & 63;
    const int n    = lane & 15;        // col within 16x16 tile
    const int q    = lane >> 4;        // quad
    const int duty = w >> 3;           // 0: score/softmax, 1: staging
    const int rh   = w & 1;            // row-half (16 rows)
    const int cb   = (w >> 1) & 3;     // comb (16-col stripe of each j-tile)
    const int pb   = w & 7;            // P buffer index = (rh,cb)

    const int blk = blockIdx.x;
    const int b   = (blk & 7) >> 1;    // XCD swizzle: batch locality in L2
    const int i0  = (((blk >> 3) << 1) | (blk & 1)) * TIW;

    // LDS: staging union (double-buffered Ks/Whs; reused as merge buffers)
    // Ks rows padded to 72 halves (144B), Whs rows padded to 72 halves.
    __shared__ __align__(16) char Ubuf[92160];
    char* KsB  = Ubuf;                 // 2 x 64*144  = 18432
    char* WhB  = Ubuf + 18432;         // 2 x 256*144 = 73728
    __shared__ half_t Pp[8][16][20];   // P per (rh,cb), padded rows
    __shared__ float  Al[32][4];       // alpha per (row, comb) per iter
    __shared__ float  Mx[32][4];       // final m per (row, comb)
    __shared__ float  Lx[32][4];       // final l per (row, comb)
    __shared__ float  qb16[16];

    if (tid < 16) qb16[tid] = qbias[tid];

    // staging: K tile (64x64 f16) + Wh^T tile (256x64 f16) into padded LDS
    auto stage = [&](int it, int base, int stride) {
        char* Ks = KsB + (it & 1) * 9216;
        char* Wh = WhB + (it & 1) * 36864;
        const int j0 = it * TJW;
        for (int idx = base; idx < 512; idx += stride) {
            const int j = idx >> 3, s = idx & 7;
            uint4 v = *(const uint4*)(Kw + (((size_t)b * NN + j0 + j) << 6) + s * 8);
            *(uint4*)(Ks + j * 144 + s * 16) = v;
        }
        for (int idx = base; idx < 2048; idx += stride) {
            const int cc = idx >> 3, s = idx & 7;
            uint4 v = *(const uint4*)(WhT + (((size_t)b * CDIM + cc) << 11) + j0 + s * 8);
            *(uint4*)(Wh + cc * 144 + s * 16) = v;
        }
    };

    // Q A-frags (persistent): row = lane&15 of this wave's row-half
    half8_t qf0, qf1;
    if (duty == 0) {
        const half_t* qsrc = Qw + (((size_t)b * NN + i0 + rh * 16 + n) << 6);
        qf0 = *(const half8_t*)(qsrc + q * 8);
        qf1 = *(const half8_t*)(qsrc + 32 + q * 8);
    }

    // bias pointers + prefetch regs (duty0)
    const int irow  = i0 + rh * 16 + q * 4;       // +r
    const int jcol0 = cb * 16 + n;                // +it*64
    const float* pmp = pm + ((size_t)b * NN + irow) * NN + jcol0;
    const float* smp = sm + ((size_t)b * NN + irow) * NN + jcol0;
    const int2*  qmp = (const int2*)qm + ((size_t)b * NN + irow) * NN + jcol0;
    float pmN[4], smN[4]; int2 qmN[4];
    if (duty == 0) {
        #pragma unroll
        for (int r = 0; r < 4; ++r) {
            pmN[r] = pmp[(size_t)r * NN];
            smN[r] = smp[(size_t)r * NN];
            qmN[r] = qmp[(size_t)r * NN];
        }
    }

    float mrun[4] = {-1e30f, -1e30f, -1e30f, -1e30f};
    float lrun[4] = {0.f, 0.f, 0.f, 0.f};
    float alr[4]  = {0.f, 0.f, 0.f, 0.f};
    f32x4 acc[8];
    #pragma unroll
    for (int t = 0; t < 8; ++t) acc[t] = (f32x4){0.f, 0.f, 0.f, 0.f};

    stage(0, tid, 1024);   // prologue staging by all waves

    for (int it = 0; it < NIT; ++it) {
        __syncthreads();                       // B_top: buf[it&1] ready
        if (duty == 1) {
            if (it + 1 < NIT) stage(it + 1, tid - 512, 512);
        } else {
            // ---- scores: one 16x16 tile, K=64 via 2 mfma ----
            const char* Ks = KsB + (it & 1) * 9216;
            const int krow = (cb * 16 + n) * 144;
            half8_t b0 = *(const half8_t*)(Ks + krow + q * 16);
            half8_t b1 = *(const half8_t*)(Ks + krow + 64 + q * 16);
            f32x4 s4 = (f32x4){0.f, 0.f, 0.f, 0.f};
            s4 = __builtin_amdgcn_mfma_f32_16x16x32_f16(qf0, b0, s4, 0, 0, 0);
            s4 = __builtin_amdgcn_mfma_f32_16x16x32_f16(qf1, b1, s4, 0, 0, 0);

            // ---- biases (prefetched) + prefetch next tile ----
            float sv[4];
            #pragma unroll
            for (int r = 0; r < 4; ++r)
                sv[r] = s4[r] + pmN[r] + smN[r] + qb16[qmN[r].x * 4 + qmN[r].y];
            if (it + 1 < NIT) {
                const int off = (it + 1) * TJW;
                #pragma unroll
                for (int r = 0; r < 4; ++r) {
                    pmN[r] = pmp[(size_t)r * NN + off];
                    smN[r] = smp[(size_t)r * NN + off];
                    qmN[r] = qmp[(size_t)r * NN + off];
                }
            }

            // ---- wave-private online softmax (rows in quads) ----
            float mx[4];
            #pragma unroll
            for (int r = 0; r < 4; ++r) mx[r] = sv[r];
            #pragma unroll
            for (int msk = 1; msk <= 8; msk <<= 1)
                #pragma unroll
                for (int r = 0; r < 4; ++r) mx[r] = fmaxf(mx[r], __shfl_xor(mx[r], msk));
            float pr[4];
            #pragma unroll
            for (int r = 0; r < 4; ++r) {
                const float mn = fmaxf(mrun[r], mx[r]);
                alr[r]  = __expf(mrun[r] - mn);
                mrun[r] = mn;
                pr[r]   = __expf(sv[r] - mn);
            }
            float se[4];
            #pragma unroll
            for (int r = 0; r < 4; ++r) se[r] = pr[r];
            #pragma unroll
            for (int msk = 1; msk <= 8; msk <<= 1)
                #pragma unroll
                for (int r = 0; r < 4; ++r) se[r] += __shfl_xor(se[r], msk);
            #pragma unroll
            for (int r = 0; r < 4; ++r) lrun[r] = lrun[r] * alr[r] + se[r];

            #pragma unroll
            for (int r = 0; r < 4; ++r) Pp[pb][q * 4 + r][n] = (half_t)pr[r];
            if (n == 0)
                #pragma unroll
                for (int r = 0; r < 4; ++r) Al[rh * 16 + q * 4 + r][cb] = alr[r];
        }
        __syncthreads();                       // B_mid: P, Al ready

        // ---- PV: O(16x128-half) += P(16x16) . Wh(16x128-half) ----
        float alv[4];
        if (duty == 0) {
            #pragma unroll
            for (int r = 0; r < 4; ++r) alv[r] = alr[r];
        } else {
            #pragma unroll
            for (int r = 0; r < 4; ++r) alv[r] = Al[rh * 16 + q * 4 + r][cb];
        }
        #pragma unroll
        for (int t = 0; t < 8; ++t)
            #pragma unroll
            for (int r = 0; r < 4; ++r) acc[t][r] *= alv[r];

        const half4_t aP = *(const half4_t*)&Pp[pb][n][q * 4];
        const char* Wh = WhB + (it & 1) * 36864;
        const int joff = cb * 32 + q * 8;      // bytes within padded row
        #pragma unroll
        for (int ct = 0; ct < 8; ++ct) {
            const half4_t bW = *(const half4_t*)(Wh + (duty * 128 + ct * 16 + n) * 144 + joff);
            acc[ct] = __builtin_amdgcn_mfma_f32_16x16x16f16(aP, bW, acc[ct], 0, 0, 0);
        }
    }

    // ---- merge combs: publish (m,l), rescale, sum partial O in LDS f32 ----
    if (duty == 0 && n == 0) {
        #pragma unroll
        for (int r = 0; r < 4; ++r) {
            Mx[rh * 16 + q * 4 + r][cb] = mrun[r];
            Lx[rh * 16 + q * 4 + r][cb] = lrun[r];
        }
    }
    __syncthreads();

    float sc[4];
    #pragma unroll
    for (int r = 0; r < 4; ++r) {
        const int row = rh * 16 + q * 4 + r;
        const f32x4 m4 = *(const f32x4*)&Mx[row][0];
        const float M = fmaxf(fmaxf(m4[0], m4[1]), fmaxf(m4[2], m4[3]));
        sc[r] = __expf(m4[cb] - M);
    }
    #pragma unroll
    for (int t = 0; t < 8; ++t)
        #pragma unroll
        for (int r = 0; r < 4; ++r) acc[t][r] *= sc[r];

    float* Buf0 = (float*)Ubuf;            // 32x256 f32
    float* Buf1 = (float*)(Ubuf + 32768);
    float* Bmy  = (cb & 1) ? Buf1 : Buf0;
    if (cb < 2) {
        #pragma unroll
        for (int ct = 0; ct < 8; ++ct)
            #pragma unroll
            for (int r = 0; r < 4; ++r)
                Bmy[(rh * 16 + q * 4 + r) * CDIM + duty * 128 + ct * 16 + n] = acc[ct][r];
    }
    __syncthreads();
    if (cb >= 2) {
        #pragma unroll
        for (int ct = 0; ct < 8; ++ct)
            #pragma unroll
            for (int r = 0; r < 4; ++r)
                Bmy[(rh * 16 + q * 4 + r) * CDIM + duty * 128 + ct * 16 + n] += acc[ct][r];
    }
    __syncthreads();
    for (int idx = tid; idx < 2048; idx += 1024) {
        f32x4 a = ((f32x4*)Buf0)[idx];
        f32x4 c = ((f32x4*)Buf1)[idx];
        ((f32x4*)Buf0)[idx] = a + c;
    }
    __syncthreads();

    // ---- epilogue: (O/l) @ outproj + ELU ----
    {
        const int o  = tid & 63;
        const int rp = tid >> 6;            // rows rp and rp+16
        const half_t* oprow = opT + o * CDIM;
        float acc0 = 0.f, acc1 = 0.f;
        #pragma unroll 4
        for (int c8 = 0; c8 < 32; ++c8) {
            const half8_t wv = *(const half8_t*)(oprow + c8 * 8);
            const f32x4 v0a = *(const f32x4*)&Buf0[rp * CDIM + c8 * 8];
            const f32x4 v0b = *(const f32x4*)&Buf0[rp * CDIM + c8 * 8 + 4];
            const f32x4 v1a = *(const f32x4*)&Buf0[(rp + 16) * CDIM + c8 * 8];
            const f32x4 v1b = *(const f32x4*)&Buf0[(rp + 16) * CDIM + c8 * 8 + 4];
            #pragma unroll
            for (int k = 0; k < 4; ++k) {
                acc0 += v0a[k] * (float)wv[k] + v0b[k] * (float)wv[k + 4];
                acc1 += v1a[k] * (float)wv[k] + v1b[k] * (float)wv[k + 4];
            }
        }
        float lt[2], rr[2] = {(float)rp, (float)(rp + 16)};
        #pragma unroll
        for (int hh = 0; hh < 2; ++hh) {
            const int row = rp + hh * 16;
            const f32x4 m4 = *(const f32x4*)&Mx[row][0];
            const f32x4 l4 = *(const f32x4*)&Lx[row][0];
            const float M = fmaxf(fmaxf(m4[0], m4[1]), fmaxf(m4[2], m4[3]));
            lt[hh] = l4[0] * __expf(m4[0] - M) + l4[1] * __expf(m4[1] - M)
                   + l4[2] * __expf(m4[2] - M) + l4[3] * __expf(m4[3] - M);
        }
        float x0 = acc0 / lt[0];
        float x1 = acc1 / lt[1];
        x0 = x0 > 0.f ? x0 : (__expf(x0) - 1.f);
        x1 = x1 > 0.f ? x1 : (__expf(x1) - 1.f);
        out[((size_t)b * NN + i0 + rp) * 64 + o]      = x0;
        out[((size_t)b * NN + i0 + rp + 16) * 64 + o] = x1;
        (void)rr;
    }
}

// ---------------------------------------------------------------------------
extern "C" void kernel_launch(void* const* d_in, const int* in_sizes, int n_in,
                              void* d_out, int out_size, void* d_ws, size_t ws_size,
                              hipStream_t stream) {
    (void)in_sizes; (void)n_in; (void)out_size; (void)ws_size;
    const float* h  = (const float*)d_in[0];
    const float* pm = (const float*)d_in[1];
    const float* sm = (const float*)d_in[2];
    const float* W  = (const float*)d_in[3];
    const float* R  = (const float*)d_in[4];
    const float* aq = (const float*)d_in[5];
    const float* ak = (const float*)d_in[6];
    const float* qb = (const float*)d_in[7];
    const float* op = (const float*)d_in[8];
    const int*   qm = (const int*)d_in[9];
    float* out = (float*)d_out;

    half_t* ws  = (half_t*)d_ws;
    half_t* Qw  = ws;                                     // 0.5M halves
    half_t* Kw  = ws + (size_t)BB * NN * 64;              // 0.5M halves
    half_t* WhT = ws + (size_t)BB * NN * 64 * 2;          // 2M halves
    half_t* opT = ws + (size_t)BB * NN * 64 * 2 + (size_t)BB * CDIM * NN; // 16K halves

    precompute_kernel<<<BB * NN / 16, 256, 0, stream>>>(h, W, R, aq, ak, Qw, Kw, WhT);
    prep_opT_kernel<<<64, 256, 0, stream>>>(op, opT);
    attn_kernel<<<BB * (NN / TIW), 1024, 0, stream>>>(Qw, Kw, WhT, pm, sm, qm, qb, opT, out);
}